// Round 1
// baseline (490.502 us; speedup 1.0000x reference)
//
#include <hip/hip_runtime.h>
#include <hip/hip_bf16.h>

// GGNN fused scan v4. B=128, N=128, E=64, T=32, R=32.
// ggnn_pre: 1024 blocks, 16 rows each; row addresses are wave-uniform ->
//   scalar s_load path; weight columns in regs. Writes NTbf (bf16) + Hws (f32).
// ggnn_main: 1 block/batch, 256 thr, 4 barriers/step, fully LDS-resident:
//   relL u8 (len-masked), relWb bf16, disc in regs, H_sw f32 XOR-swizzled.
//   Gate/H matvecs via v_readlane (no LDS pipe, no broadcast b128).
//   NT read from global bf16 with 1-step register prefetch (crosses 3+
//   barriers before use -> vmcnt drain is free).
//   w0=r, w1=z, w2=t+upd(+user/item/sub), w3=H-row. Steps i>=len are no-ops.

#define B_ 128
#define N_ 128
#define SW(ee) (((ee) & 7) << 2)   // XOR swizzle: phys_j = j ^ SW(e)

typedef unsigned short u16;
typedef unsigned int u32;

__device__ __forceinline__ float b2f(u16 u) {
    union { u32 i; float f; } c; c.i = ((u32)u) << 16; return c.f;
}
__device__ __forceinline__ u16 f2b(float f) {
    union { float f; u32 i; } c; c.f = f;
    u32 u = c.i;
    return (u16)((u + 0x7fffu + ((u >> 16) & 1u)) >> 16);
}
__device__ __forceinline__ float sigmoidf_(float x) { return 1.0f / (1.0f + __expf(-x)); }
__device__ __forceinline__ float tanhf_(float x) { return 1.0f - 2.0f / (__expf(2.0f * x) + 1.0f); }
__device__ __forceinline__ float rlane(float v, int k) {
    return __int_as_float(__builtin_amdgcn_readlane(__float_as_int(v), k));
}

// ---------------- precompute kernel ----------------
__global__ __launch_bounds__(256, 2) void ggnn_pre(
    const int* __restrict__ node_slice, const int* __restrict__ type_slice,
    const float* __restrict__ emb_table, const float* __restrict__ type_table,
    const float* __restrict__ W_in,
    const float* __restrict__ Wr, const float* __restrict__ br,
    const float* __restrict__ Wz, const float* __restrict__ bz,
    const float* __restrict__ Wt, const float* __restrict__ bt,
    u16* __restrict__ NTbf, float* __restrict__ Hws)
{
    const int b  = blockIdx.x >> 3;
    const int i0 = (blockIdx.x & 7) * 16;
    const int t = threadIdx.x;
    const int w = t >> 6;
    const int e = t & 63;

    float wc[96];
    float bias = 0.f;
    if (w < 3) {
        const float* W  = (w == 0) ? Wr : (w == 1) ? Wz : Wt;
        const float* bb = (w == 0) ? br : (w == 1) ? bz : bt;
        bias = bb[e];
        #pragma unroll
        for (int k = 0; k < 96; ++k) wc[k] = W[k * 64 + e];
    } else {
        #pragma unroll
        for (int k = 0; k < 64; ++k) wc[k] = W_in[k * 64 + e];
        #pragma unroll
        for (int k = 64; k < 96; ++k) wc[k] = 0.f;
    }

    for (int rr = 0; rr < 16; ++rr) {
        const int row = i0 + rr;
        const int node = node_slice[b * N_ + row];   // uniform -> s_load path
        const float* ep = emb_table + node * 64;
        if (w < 3) {
            const int typ = type_slice[b * N_ + row];
            const float* tp = type_table + typ * 32;
            float a0 = bias, a1 = 0.f, a2 = 0.f, a3 = 0.f;
            #pragma unroll
            for (int k = 0; k < 32; k += 4) {
                a0 += tp[k]   * wc[k];
                a1 += tp[k+1] * wc[k+1];
                a2 += tp[k+2] * wc[k+2];
                a3 += tp[k+3] * wc[k+3];
            }
            #pragma unroll
            for (int k = 0; k < 64; k += 4) {
                a0 += ep[k]   * wc[32+k];
                a1 += ep[k+1] * wc[32+k+1];
                a2 += ep[k+2] * wc[32+k+2];
                a3 += ep[k+3] * wc[32+k+3];
            }
            NTbf[(b * N_ + row) * 192 + w * 64 + e] = f2b((a0 + a1) + (a2 + a3));
        } else {
            float a0 = 0.f, a1 = 0.f, a2 = 0.f, a3 = 0.f;
            #pragma unroll
            for (int k = 0; k < 64; k += 4) {
                a0 += ep[k]   * wc[k];
                a1 += ep[k+1] * wc[k+1];
                a2 += ep[k+2] * wc[k+2];
                a3 += ep[k+3] * wc[k+3];
            }
            Hws[(b * N_ + row) * 64 + e] = (a0 + a1) + (a2 + a3);
        }
    }
}

// ---------------- main scan kernel ----------------
__global__ __launch_bounds__(256, 1) void ggnn_main(
    const int* __restrict__ rel_matrix,
    const int* __restrict__ input_length, const float* __restrict__ distance,
    const float* __restrict__ rel_table,
    const float* __restrict__ W_in, const float* __restrict__ b_in,
    const float* __restrict__ Wr, const float* __restrict__ Wz, const float* __restrict__ Wt,
    const float* __restrict__ W_co, const float* __restrict__ b_co,
    const float* __restrict__ W1, const float* __restrict__ b1,
    const float* __restrict__ W2, const float* __restrict__ b2,
    const float* __restrict__ W3, const float* __restrict__ b3,
    const float* __restrict__ W4, const float* __restrict__ b4,
    const u16* __restrict__ NTbf, const float* __restrict__ Hws,
    float* __restrict__ out)
{
    __shared__ __align__(16) float H_sw[64 * 128];        // 32 KB, XOR-swizzled
    __shared__ __align__(16) u16   relWb16[51 * 64];      // 6.4 KB, [r][e] bf16
    __shared__ __align__(16) unsigned char relL[128 * 128]; // 16 KB, len-masked
    __shared__ __align__(16) float disc[N_];
    __shared__ __align__(16) float pmax[256];
    __shared__ __align__(16) float r_row[64], z_row[64], updrow[64];
    __shared__ __align__(16) float userrow[64], itemrow[64], submrow[64];
    __shared__ __align__(16) float temp[192];
    __shared__ float h1[128];
    __shared__ float h2v[64];
    __shared__ float h3v[32];

    const int b = blockIdx.x;
    const int t = threadIdx.x;
    const int w = t >> 6;
    const int e = t & 63;
    const int len = input_length[b];
    const float NEGINF = -__builtin_inff();

    // ---- staging ----
    if (t < N_) disc[t] = -0.1f * distance[b * N_ + t];

    {   // rel_matrix -> u8, len-masked
        const int4* src = (const int4*)(rel_matrix + b * N_ * N_);
        u32* dst = (u32*)relL;
        for (int c = t; c < 4096; c += 256) {
            int4 v = src[c];
            int j = (c * 4) & 127;
            u32 p = (u32)((j + 0 < len && v.x) ? v.x : 0)
                  | ((u32)((j + 1 < len && v.y) ? v.y : 0) << 8)
                  | ((u32)((j + 2 < len && v.z) ? v.z : 0) << 16)
                  | ((u32)((j + 3 < len && v.w) ? v.w : 0) << 24);
            dst[c] = p;
        }
    }
    for (int idx = t; idx < N_ * 64; idx += 256) {        // H_sw <- Hws
        int j = idx >> 6, ee = idx & 63;
        H_sw[(ee << 7) + (j ^ SW(ee))] = Hws[b * N_ * 64 + idx];
    }
    for (int idx = t; idx < 51 * 64; idx += 256) {        // relWb = b_in + rel@W_in_bot
        int r = idx >> 6, ee = idx & 63;
        float acc = b_in[ee];
        #pragma unroll
        for (int k = 0; k < 32; ++k)
            acc += rel_table[r * 32 + k] * W_in[(64 + k) * 64 + ee];
        relWb16[idx] = f2b(acc);
    }

    // per-wave weight column: w0=Wr_bot, w1=Wz_bot, w2=Wt_bot, w3=W_in_top
    float wcol[64];
    {
        const float* wsrc = (w == 0) ? (Wr + 96 * 64) : (w == 1) ? (Wz + 96 * 64)
                          : (w == 2) ? (Wt + 96 * 64) : W_in;
        #pragma unroll
        for (int k = 0; k < 64; ++k) wcol[k] = wsrc[k * 64 + e];
    }

    // NT prefetch (step 0)
    const u16* NTb = NTbf + b * N_ * 192;
    u16 ntc = 0;
    if (w < 3) ntc = NTb[w * 64 + e];
    float user_r = 0.f, item_r = 0.f, subm_r = NEGINF;
    __syncthreads();                                      // A0

    // disc -> regs (after barrier)
    float dreg[32];
    #pragma unroll
    for (int jj = 0; jj < 32; ++jj) dreg[jj] = disc[w * 32 + jj];

    const int sw = SW(e);
    const float* hrow = H_sw + (e << 7);

    // ---- scan ----
    for (int i = 0; i < len; ++i) {
        // max phase: all 4 waves, 32 j each, LDS-resident
        const u32* rrow = (const u32*)(relL + i * 128 + w * 32);
        float m = NEGINF;
        #pragma unroll
        for (int g = 0; g < 8; ++g) {
            u32 d = rrow[g];
            const int j0 = w * 32 + 4 * g;
            float4 hv = *(const float4*)(hrow + (j0 ^ sw));
            int r0 = d & 255, r1 = (d >> 8) & 255, r2 = (d >> 16) & 255, r3 = d >> 24;
            float s0 = fmaxf(hv.x + b2f(relWb16[(r0 << 6) + e]), 0.f) * dreg[4*g+0];
            float s1 = fmaxf(hv.y + b2f(relWb16[(r1 << 6) + e]), 0.f) * dreg[4*g+1];
            float s2 = fmaxf(hv.z + b2f(relWb16[(r2 << 6) + e]), 0.f) * dreg[4*g+2];
            float s3 = fmaxf(hv.w + b2f(relWb16[(r3 << 6) + e]), 0.f) * dreg[4*g+3];
            m = r0 ? fmaxf(m, s0) : m;
            m = r1 ? fmaxf(m, s1) : m;
            m = r2 ? fmaxf(m, s2) : m;
            m = r3 ? fmaxf(m, s3) : m;
        }
        pmax[t] = m;
        __syncthreads();                                  // B

        float mm = fmaxf(fmaxf(pmax[e], pmax[64 + e]),
                         fmaxf(pmax[128 + e], pmax[192 + e]));
        float dis0 = (mm == NEGINF) ? 0.f : mm;

        // NT prefetch for step i+1 (consumed after 3+ barriers -> drain free)
        u16 ntp = 0;
        if (w < 3) ntp = NTb[((i + 1) & 127) * 192 + w * 64 + e];

        if (w == 0) {                                     // r-gate (readlane matvec)
            float a0 = b2f(ntc), a1 = 0.f, a2 = 0.f, a3 = 0.f;
            #pragma unroll
            for (int k = 0; k < 64; k += 4) {
                a0 += rlane(dis0, k)     * wcol[k];
                a1 += rlane(dis0, k + 1) * wcol[k + 1];
                a2 += rlane(dis0, k + 2) * wcol[k + 2];
                a3 += rlane(dis0, k + 3) * wcol[k + 3];
            }
            r_row[e] = sigmoidf_((a0 + a1) + (a2 + a3));
        } else if (w == 1) {                              // z-gate
            float a0 = b2f(ntc), a1 = 0.f, a2 = 0.f, a3 = 0.f;
            #pragma unroll
            for (int k = 0; k < 64; k += 4) {
                a0 += rlane(dis0, k)     * wcol[k];
                a1 += rlane(dis0, k + 1) * wcol[k + 1];
                a2 += rlane(dis0, k + 2) * wcol[k + 2];
                a3 += rlane(dis0, k + 3) * wcol[k + 3];
            }
            z_row[e] = sigmoidf_((a0 + a1) + (a2 + a3));
        }
        __syncthreads();                                  // C

        if (w == 2) {                                     // t-gate + update
            float rdp = r_row[e] * dis0;
            float a0 = b2f(ntc), a1 = 0.f, a2 = 0.f, a3 = 0.f;
            #pragma unroll
            for (int k = 0; k < 64; k += 4) {
                a0 += rlane(rdp, k)     * wcol[k];
                a1 += rlane(rdp, k + 1) * wcol[k + 1];
                a2 += rlane(rdp, k + 2) * wcol[k + 2];
                a3 += rlane(rdp, k + 3) * wcol[k + 3];
            }
            float hh = tanhf_((a0 + a1) + (a2 + a3));
            float z = z_row[e];
            float upd = (1.f - z) * dis0 + z * hh;
            updrow[e] = upd;
            if (i == 0) user_r = upd;
            subm_r = fmaxf(subm_r, upd);
            item_r = upd;
        }
        __syncthreads();                                  // D

        if (w == 3) {                                     // H-row update
            float u = updrow[e];
            float a0 = 0.f, a1 = 0.f, a2 = 0.f, a3 = 0.f;
            #pragma unroll
            for (int k = 0; k < 64; k += 4) {
                a0 += rlane(u, k)     * wcol[k];
                a1 += rlane(u, k + 1) * wcol[k + 1];
                a2 += rlane(u, k + 2) * wcol[k + 2];
                a3 += rlane(u, k + 3) * wcol[k + 3];
            }
            H_sw[(e << 7) + (i ^ sw)] = (a0 + a1) + (a2 + a3);
        }
        ntc = ntp;
        __syncthreads();                                  // A (loop top)
    }

    if (w == 2) { userrow[e] = user_r; itemrow[e] = item_r; submrow[e] = subm_r; }
    __syncthreads();

    // ---- epilogue ----
    if (t < 128) {
        const int half = t >> 6;                // 0: ua*user, 1: ia*item
        const float* row = (half == 0) ? userrow : itemrow;
        float acc = b_co[e];
        #pragma unroll
        for (int k = 0; k < 64; ++k) acc += row[k] * W_co[k * 64 + e];
        #pragma unroll
        for (int k = 0; k < 64; ++k) acc += submrow[k] * W_co[(64 + k) * 64 + e];
        float act = fmaxf(acc, 0.f);
        temp[half * 128 + e] = act * row[e];
    } else if (t < 192) {
        temp[64 + (t - 128)] = submrow[t - 128];
    }
    __syncthreads();

    if (t < 128) {
        float acc = b1[t];
        for (int k = 0; k < 192; ++k) acc += temp[k] * W1[k * 128 + t];
        h1[t] = fmaxf(acc, 0.f);
    }
    __syncthreads();
    if (t < 64) {
        float acc = b2[t];
        for (int k = 0; k < 128; ++k) acc += h1[k] * W2[k * 64 + t];
        h2v[t] = fmaxf(acc, 0.f);
    }
    __syncthreads();
    if (t < 32) {
        float acc = b3[t];
        for (int k = 0; k < 64; ++k) acc += h2v[k] * W3[k * 32 + t];
        h3v[t] = fmaxf(acc, 0.f);
    }
    __syncthreads();
    if (t == 0) {
        float acc = b4[0];
        for (int k = 0; k < 32; ++k) acc += h3v[k] * W4[k];
        out[b] = sigmoidf_(acc);
    }
}

extern "C" void kernel_launch(void* const* d_in, const int* in_sizes, int n_in,
                              void* d_out, int out_size, void* d_ws, size_t ws_size,
                              hipStream_t stream)
{
    const int*   node_slice = (const int*)d_in[0];
    const int*   type_slice = (const int*)d_in[1];
    const float* distance   = (const float*)d_in[2];
    const int*   rel_matrix = (const int*)d_in[3];
    const int*   input_len  = (const int*)d_in[4];
    // d_in[5] = isBatch (ignored)
    const float* emb_table  = (const float*)d_in[6];
    const float* type_table = (const float*)d_in[7];
    const float* rel_table  = (const float*)d_in[8];
    const float* W_in = (const float*)d_in[9];  const float* b_in = (const float*)d_in[10];
    const float* Wr   = (const float*)d_in[11]; const float* br   = (const float*)d_in[12];
    const float* Wz   = (const float*)d_in[13]; const float* bz   = (const float*)d_in[14];
    const float* Wt   = (const float*)d_in[15]; const float* bt   = (const float*)d_in[16];
    const float* W_co = (const float*)d_in[17]; const float* b_co = (const float*)d_in[18];
    const float* W1   = (const float*)d_in[19]; const float* b1   = (const float*)d_in[20];
    const float* W2   = (const float*)d_in[21]; const float* b2   = (const float*)d_in[22];
    const float* W3   = (const float*)d_in[23]; const float* b3   = (const float*)d_in[24];
    const float* W4   = (const float*)d_in[25]; const float* b4   = (const float*)d_in[26];

    u16*   NTbf = (u16*)d_ws;                            // 128*128*192 bf16 = 6.29 MB
    float* Hws  = (float*)((char*)d_ws + (size_t)B_ * N_ * 192 * 2); // 4.19 MB

    ggnn_pre<<<dim3(1024), dim3(256), 0, stream>>>(
        node_slice, type_slice, emb_table, type_table,
        W_in, Wr, br, Wz, bz, Wt, bt, NTbf, Hws);

    ggnn_main<<<dim3(B_), dim3(256), 0, stream>>>(
        rel_matrix, input_len, distance, rel_table,
        W_in, b_in, Wr, Wz, Wt, W_co, b_co,
        W1, b1, W2, b2, W3, b3, W4, b4,
        NTbf, Hws, (float*)d_out);
}

// Round 2
// 476.653 us; speedup vs baseline: 1.0291x; 1.0291x over previous
//
#include <hip/hip_runtime.h>
#include <hip/hip_bf16.h>

// GGNN fused scan v5. B=128, N=128, E=64, T=32, R=32.
// ggnn_pre: unchanged from v4.
// ggnn_main v5: 3 barriers/step (was 4). H-row matvec (w3) runs concurrently
//   with the NEXT step's max phase: w0-2 cover j in [0,36)/[36,72)/[72,108)
//   (masking out j==i-1), w3 computes H(i-1) from updrow, writes it, adds the
//   j==i-1 contribution from registers, then covers j in [108,128).
//   NT prefetch issued at TOP of max phase so the vmcnt(0) drain at barrier B
//   is covered by ~800cy of max-phase work (previously exposed at barrier C).

#define B_ 128
#define N_ 128
#define SW(ee) (((ee) & 7) << 2)   // XOR swizzle: phys_j = j ^ SW(e)

typedef unsigned short u16;
typedef unsigned int u32;

__device__ __forceinline__ float b2f(u16 u) {
    union { u32 i; float f; } c; c.i = ((u32)u) << 16; return c.f;
}
__device__ __forceinline__ u16 f2b(float f) {
    union { float f; u32 i; } c; c.f = f;
    u32 u = c.i;
    return (u16)((u + 0x7fffu + ((u >> 16) & 1u)) >> 16);
}
__device__ __forceinline__ float sigmoidf_(float x) { return 1.0f / (1.0f + __expf(-x)); }
__device__ __forceinline__ float tanhf_(float x) { return 1.0f - 2.0f / (__expf(2.0f * x) + 1.0f); }
__device__ __forceinline__ float rlane(float v, int k) {
    return __int_as_float(__builtin_amdgcn_readlane(__float_as_int(v), k));
}

// Max over G u32-packed rel groups starting at word `baseword` (global j =
// jstart + 4g). Word index S (global) gets byte-mask kmask applied (skips
// j == i-1; S = -1 matches nothing).
template<int G>
__device__ __forceinline__ float max_over(
    const u32* __restrict__ rrow, const float* __restrict__ hrow, int sw,
    const u16* __restrict__ relWb, const float* __restrict__ dreg, int e,
    int baseword, int S, u32 kmask, int jstart, float m)
{
    #pragma unroll
    for (int g = 0; g < G; ++g) {
        u32 d = rrow[g];
        d = (baseword + g == S) ? (d & kmask) : d;
        const int j0 = jstart + 4 * g;
        float4 hv = *(const float4*)(hrow + (j0 ^ sw));
        int r0 = d & 255, r1 = (d >> 8) & 255, r2 = (d >> 16) & 255, r3 = d >> 24;
        float s0 = fmaxf(hv.x + b2f(relWb[(r0 << 6) + e]), 0.f) * dreg[4*g+0];
        float s1 = fmaxf(hv.y + b2f(relWb[(r1 << 6) + e]), 0.f) * dreg[4*g+1];
        float s2 = fmaxf(hv.z + b2f(relWb[(r2 << 6) + e]), 0.f) * dreg[4*g+2];
        float s3 = fmaxf(hv.w + b2f(relWb[(r3 << 6) + e]), 0.f) * dreg[4*g+3];
        m = r0 ? fmaxf(m, s0) : m;
        m = r1 ? fmaxf(m, s1) : m;
        m = r2 ? fmaxf(m, s2) : m;
        m = r3 ? fmaxf(m, s3) : m;
    }
    return m;
}

// ---------------- precompute kernel ----------------
__global__ __launch_bounds__(256, 2) void ggnn_pre(
    const int* __restrict__ node_slice, const int* __restrict__ type_slice,
    const float* __restrict__ emb_table, const float* __restrict__ type_table,
    const float* __restrict__ W_in,
    const float* __restrict__ Wr, const float* __restrict__ br,
    const float* __restrict__ Wz, const float* __restrict__ bz,
    const float* __restrict__ Wt, const float* __restrict__ bt,
    u16* __restrict__ NTbf, float* __restrict__ Hws)
{
    const int b  = blockIdx.x >> 3;
    const int i0 = (blockIdx.x & 7) * 16;
    const int t = threadIdx.x;
    const int w = t >> 6;
    const int e = t & 63;

    float wc[96];
    float bias = 0.f;
    if (w < 3) {
        const float* W  = (w == 0) ? Wr : (w == 1) ? Wz : Wt;
        const float* bb = (w == 0) ? br : (w == 1) ? bz : bt;
        bias = bb[e];
        #pragma unroll
        for (int k = 0; k < 96; ++k) wc[k] = W[k * 64 + e];
    } else {
        #pragma unroll
        for (int k = 0; k < 64; ++k) wc[k] = W_in[k * 64 + e];
        #pragma unroll
        for (int k = 64; k < 96; ++k) wc[k] = 0.f;
    }

    for (int rr = 0; rr < 16; ++rr) {
        const int row = i0 + rr;
        const int node = node_slice[b * N_ + row];   // uniform -> s_load path
        const float* ep = emb_table + node * 64;
        if (w < 3) {
            const int typ = type_slice[b * N_ + row];
            const float* tp = type_table + typ * 32;
            float a0 = bias, a1 = 0.f, a2 = 0.f, a3 = 0.f;
            #pragma unroll
            for (int k = 0; k < 32; k += 4) {
                a0 += tp[k]   * wc[k];
                a1 += tp[k+1] * wc[k+1];
                a2 += tp[k+2] * wc[k+2];
                a3 += tp[k+3] * wc[k+3];
            }
            #pragma unroll
            for (int k = 0; k < 64; k += 4) {
                a0 += ep[k]   * wc[32+k];
                a1 += ep[k+1] * wc[32+k+1];
                a2 += ep[k+2] * wc[32+k+2];
                a3 += ep[k+3] * wc[32+k+3];
            }
            NTbf[(b * N_ + row) * 192 + w * 64 + e] = f2b((a0 + a1) + (a2 + a3));
        } else {
            float a0 = 0.f, a1 = 0.f, a2 = 0.f, a3 = 0.f;
            #pragma unroll
            for (int k = 0; k < 64; k += 4) {
                a0 += ep[k]   * wc[k];
                a1 += ep[k+1] * wc[k+1];
                a2 += ep[k+2] * wc[k+2];
                a3 += ep[k+3] * wc[k+3];
            }
            Hws[(b * N_ + row) * 64 + e] = (a0 + a1) + (a2 + a3);
        }
    }
}

// ---------------- main scan kernel ----------------
__global__ __launch_bounds__(256, 1) void ggnn_main(
    const int* __restrict__ rel_matrix,
    const int* __restrict__ input_length, const float* __restrict__ distance,
    const float* __restrict__ rel_table,
    const float* __restrict__ W_in, const float* __restrict__ b_in,
    const float* __restrict__ Wr, const float* __restrict__ Wz, const float* __restrict__ Wt,
    const float* __restrict__ W_co, const float* __restrict__ b_co,
    const float* __restrict__ W1, const float* __restrict__ b1,
    const float* __restrict__ W2, const float* __restrict__ b2,
    const float* __restrict__ W3, const float* __restrict__ b3,
    const float* __restrict__ W4, const float* __restrict__ b4,
    const u16* __restrict__ NTbf, const float* __restrict__ Hws,
    float* __restrict__ out)
{
    __shared__ __align__(16) float H_sw[64 * 128];        // 32 KB, XOR-swizzled
    __shared__ __align__(16) u16   relWb16[51 * 64];      // 6.4 KB, [r][e] bf16
    __shared__ __align__(16) unsigned char relL[128 * 128]; // 16 KB, len-masked
    __shared__ __align__(16) float disc[N_];
    __shared__ __align__(16) float pmax[256];
    __shared__ __align__(16) float r_row[64], z_row[64], updrow[64];
    __shared__ __align__(16) float userrow[64], itemrow[64], submrow[64];
    __shared__ __align__(16) float temp[192];
    __shared__ float h1[128];
    __shared__ float h2v[64];
    __shared__ float h3v[32];

    const int b = blockIdx.x;
    const int t = threadIdx.x;
    const int w = t >> 6;
    const int e = t & 63;
    const int len = input_length[b];
    const float NEGINF = -__builtin_inff();

    // ---- staging ----
    if (t < N_) disc[t] = -0.1f * distance[b * N_ + t];

    {   // rel_matrix -> u8, len-masked
        const int4* src = (const int4*)(rel_matrix + b * N_ * N_);
        u32* dst = (u32*)relL;
        for (int c = t; c < 4096; c += 256) {
            int4 v = src[c];
            int j = (c * 4) & 127;
            u32 p = (u32)((j + 0 < len && v.x) ? v.x : 0)
                  | ((u32)((j + 1 < len && v.y) ? v.y : 0) << 8)
                  | ((u32)((j + 2 < len && v.z) ? v.z : 0) << 16)
                  | ((u32)((j + 3 < len && v.w) ? v.w : 0) << 24);
            dst[c] = p;
        }
    }
    for (int idx = t; idx < N_ * 64; idx += 256) {        // H_sw <- Hws
        int j = idx >> 6, ee = idx & 63;
        H_sw[(ee << 7) + (j ^ SW(ee))] = Hws[b * N_ * 64 + idx];
    }
    for (int idx = t; idx < 51 * 64; idx += 256) {        // relWb = b_in + rel@W_in_bot
        int r = idx >> 6, ee = idx & 63;
        float acc = b_in[ee];
        #pragma unroll
        for (int k = 0; k < 32; ++k)
            acc += rel_table[r * 32 + k] * W_in[(64 + k) * 64 + ee];
        relWb16[idx] = f2b(acc);
    }

    // per-wave weight column: w0=Wr_bot, w1=Wz_bot, w2=Wt_bot, w3=W_in_top
    float wcol[64];
    {
        const float* wsrc = (w == 0) ? (Wr + 96 * 64) : (w == 1) ? (Wz + 96 * 64)
                          : (w == 2) ? (Wt + 96 * 64) : W_in;
        #pragma unroll
        for (int k = 0; k < 64; ++k) wcol[k] = wsrc[k * 64 + e];
    }

    // NT prefetch (step 0)
    const u16* NTb = NTbf + b * N_ * 192;
    u16 ntc = 0;
    if (w < 3) ntc = NTb[w * 64 + e];
    float user_r = 0.f, item_r = 0.f, subm_r = NEGINF;
    __syncthreads();                                      // A0

    // per-wave j-range: w0 [0,36), w1 [36,72), w2 [72,108), w3 [108,128)
    const int jstart = (w < 3) ? w * 36 : 108;
    const int baseword = jstart >> 2;
    float dreg[36];
    #pragma unroll
    for (int jj = 0; jj < 36; ++jj) {
        int j = jstart + jj;
        dreg[jj] = (j < N_) ? disc[j] : 0.f;
    }

    const int sw = SW(e);
    const float* hrow = H_sw + (e << 7);

    // ---- scan ----
    // Loop invariant at top of step i (after barrier A): updrow = upd(i-1)
    // (for i>0); H_sw rows 0..i-2 updated, row i-1 pending (w3 writes it in P1).
    for (int i = 0; i < len; ++i) {
        // NT prefetch for step i+1, issued FIRST so the vmcnt drain at
        // barrier B is covered by the max/H phase (~800cy).
        u16 ntp = 0;
        if (w < 3) ntp = NTb[((i + 1) & 127) * 192 + w * 64 + e];

        const int S = (i - 1) >> 2;                        // -1 when i==0
        const u32 kmask = ~(0xFFu << (((i - 1) & 3) * 8));
        const u32* rrow = (const u32*)(relL + i * 128) + baseword;
        float m = NEGINF;

        if (w < 3) {
            m = max_over<9>(rrow, hrow, sw, relWb16, dreg, e,
                            baseword, S, kmask, jstart, m);
        } else {
            if (i > 0) {                                   // H-row(i-1) matvec
                float u = updrow[e];
                float a0 = 0.f, a1 = 0.f, a2 = 0.f, a3 = 0.f;
                #pragma unroll
                for (int k = 0; k < 64; k += 4) {
                    a0 += rlane(u, k)     * wcol[k];
                    a1 += rlane(u, k + 1) * wcol[k + 1];
                    a2 += rlane(u, k + 2) * wcol[k + 2];
                    a3 += rlane(u, k + 3) * wcol[k + 3];
                }
                float aH = (a0 + a1) + (a2 + a3);
                H_sw[(e << 7) + ((i - 1) ^ sw)] = aH;
                // j == i-1 contribution from fresh registers
                int rb = relL[i * 128 + (i - 1)];          // uniform broadcast
                if (rb) {
                    float s = fmaxf(aH + b2f(relWb16[(rb << 6) + e]), 0.f)
                              * disc[i - 1];
                    m = fmaxf(m, s);
                }
            }
            m = max_over<5>(rrow, hrow, sw, relWb16, dreg, e,
                            baseword, S, kmask, jstart, m);
        }
        pmax[(w << 6) + e] = m;
        __syncthreads();                                  // B

        float mm = fmaxf(fmaxf(pmax[e], pmax[64 + e]),
                         fmaxf(pmax[128 + e], pmax[192 + e]));
        float dis0 = (mm == NEGINF) ? 0.f : mm;

        if (w == 0) {                                     // r-gate
            float a0 = b2f(ntc), a1 = 0.f, a2 = 0.f, a3 = 0.f;
            #pragma unroll
            for (int k = 0; k < 64; k += 4) {
                a0 += rlane(dis0, k)     * wcol[k];
                a1 += rlane(dis0, k + 1) * wcol[k + 1];
                a2 += rlane(dis0, k + 2) * wcol[k + 2];
                a3 += rlane(dis0, k + 3) * wcol[k + 3];
            }
            r_row[e] = sigmoidf_((a0 + a1) + (a2 + a3));
        } else if (w == 1) {                              // z-gate
            float a0 = b2f(ntc), a1 = 0.f, a2 = 0.f, a3 = 0.f;
            #pragma unroll
            for (int k = 0; k < 64; k += 4) {
                a0 += rlane(dis0, k)     * wcol[k];
                a1 += rlane(dis0, k + 1) * wcol[k + 1];
                a2 += rlane(dis0, k + 2) * wcol[k + 2];
                a3 += rlane(dis0, k + 3) * wcol[k + 3];
            }
            z_row[e] = sigmoidf_((a0 + a1) + (a2 + a3));
        }
        __syncthreads();                                  // C

        if (w == 2) {                                     // t-gate + update
            float rdp = r_row[e] * dis0;
            float a0 = b2f(ntc), a1 = 0.f, a2 = 0.f, a3 = 0.f;
            #pragma unroll
            for (int k = 0; k < 64; k += 4) {
                a0 += rlane(rdp, k)     * wcol[k];
                a1 += rlane(rdp, k + 1) * wcol[k + 1];
                a2 += rlane(rdp, k + 2) * wcol[k + 2];
                a3 += rlane(rdp, k + 3) * wcol[k + 3];
            }
            float hh = tanhf_((a0 + a1) + (a2 + a3));
            float z = z_row[e];
            float upd = (1.f - z) * dis0 + z * hh;
            updrow[e] = upd;
            if (i == 0) user_r = upd;
            subm_r = fmaxf(subm_r, upd);
            item_r = upd;
        }
        ntc = ntp;
        __syncthreads();                                  // A (loop top)
    }

    if (w == 2) { userrow[e] = user_r; itemrow[e] = item_r; submrow[e] = subm_r; }
    __syncthreads();

    // ---- epilogue ----
    if (t < 128) {
        const int half = t >> 6;                // 0: ua*user, 1: ia*item
        const float* row = (half == 0) ? userrow : itemrow;
        float acc = b_co[e];
        #pragma unroll
        for (int k = 0; k < 64; ++k) acc += row[k] * W_co[k * 64 + e];
        #pragma unroll
        for (int k = 0; k < 64; ++k) acc += submrow[k] * W_co[(64 + k) * 64 + e];
        float act = fmaxf(acc, 0.f);
        temp[half * 128 + e] = act * row[e];
    } else if (t < 192) {
        temp[64 + (t - 128)] = submrow[t - 128];
    }
    __syncthreads();

    if (t < 128) {
        float acc = b1[t];
        for (int k = 0; k < 192; ++k) acc += temp[k] * W1[k * 128 + t];
        h1[t] = fmaxf(acc, 0.f);
    }
    __syncthreads();
    if (t < 64) {
        float acc = b2[t];
        for (int k = 0; k < 128; ++k) acc += h1[k] * W2[k * 64 + t];
        h2v[t] = fmaxf(acc, 0.f);
    }
    __syncthreads();
    if (t < 32) {
        float acc = b3[t];
        for (int k = 0; k < 64; ++k) acc += h2v[k] * W3[k * 32 + t];
        h3v[t] = fmaxf(acc, 0.f);
    }
    __syncthreads();
    if (t == 0) {
        float acc = b4[0];
        for (int k = 0; k < 32; ++k) acc += h3v[k] * W4[k];
        out[b] = sigmoidf_(acc);
    }
}

extern "C" void kernel_launch(void* const* d_in, const int* in_sizes, int n_in,
                              void* d_out, int out_size, void* d_ws, size_t ws_size,
                              hipStream_t stream)
{
    const int*   node_slice = (const int*)d_in[0];
    const int*   type_slice = (const int*)d_in[1];
    const float* distance   = (const float*)d_in[2];
    const int*   rel_matrix = (const int*)d_in[3];
    const int*   input_len  = (const int*)d_in[4];
    // d_in[5] = isBatch (ignored)
    const float* emb_table  = (const float*)d_in[6];
    const float* type_table = (const float*)d_in[7];
    const float* rel_table  = (const float*)d_in[8];
    const float* W_in = (const float*)d_in[9];  const float* b_in = (const float*)d_in[10];
    const float* Wr   = (const float*)d_in[11]; const float* br   = (const float*)d_in[12];
    const float* Wz   = (const float*)d_in[13]; const float* bz   = (const float*)d_in[14];
    const float* Wt   = (const float*)d_in[15]; const float* bt   = (const float*)d_in[16];
    const float* W_co = (const float*)d_in[17]; const float* b_co = (const float*)d_in[18];
    const float* W1   = (const float*)d_in[19]; const float* b1   = (const float*)d_in[20];
    const float* W2   = (const float*)d_in[21]; const float* b2   = (const float*)d_in[22];
    const float* W3   = (const float*)d_in[23]; const float* b3   = (const float*)d_in[24];
    const float* W4   = (const float*)d_in[25]; const float* b4   = (const float*)d_in[26];

    u16*   NTbf = (u16*)d_ws;                            // 128*128*192 bf16 = 6.29 MB
    float* Hws  = (float*)((char*)d_ws + (size_t)B_ * N_ * 192 * 2); // 4.19 MB

    ggnn_pre<<<dim3(1024), dim3(256), 0, stream>>>(
        node_slice, type_slice, emb_table, type_table,
        W_in, Wr, br, Wz, bz, Wt, bt, NTbf, Hws);

    ggnn_main<<<dim3(B_), dim3(256), 0, stream>>>(
        rel_matrix, input_len, distance, rel_table,
        W_in, b_in, Wr, Wz, Wt, W_co, b_co,
        W1, b1, W2, b2, W3, b3, W4, b4,
        NTbf, Hws, (float*)d_out);
}

// Round 3
// 466.998 us; speedup vs baseline: 1.0503x; 1.0207x over previous
//
#include <hip/hip_runtime.h>
#include <hip/hip_bf16.h>

// GGNN fused scan v6. B=128, N=128, E=64, T=32, R=32.
// ggnn_pre: unchanged.
// ggnn_main v6: LDS-pipe diet for the scan.
//   - H matrix in REGISTERS: wave w owns j in [32w,32w+32); lane (p,half)
//     holds e-pair (2p,2p+1) for 16 j. No H_sw LDS, no hv b128 reads.
//   - relW stored as u32 e-pairs [51][32]: gather = 16 ds_read_b32/wave/step
//     (bank = p -> conflict-free). Pair->lane-e combine via 4 ds_bpermute.
//   - Phases: P1 max (+owner merges row i-1 from updH1+updH2) | B |
//     P2 r,z gates (w0,w1) | C | P3a t+upd (w2) || part1=(1-z)dis0@Win (w3)
//     | D | P3b part2=(z*hh)@Win (w3) | A.
//   - Raw s_barrier + lgkmcnt(0) only (no vmcnt drain): NT global prefetch
//     issued 1 full step ahead, never exposed.

#define B_ 128
#define N_ 128

typedef unsigned short u16;
typedef unsigned int u32;

__device__ __forceinline__ float b2f(u16 u) {
    union { u32 i; float f; } c; c.i = ((u32)u) << 16; return c.f;
}
__device__ __forceinline__ u16 f2b(float f) {
    union { float f; u32 i; } c; c.f = f;
    u32 u = c.i;
    return (u16)((u + 0x7fffu + ((u >> 16) & 1u)) >> 16);
}
__device__ __forceinline__ float sigmoidf_(float x) { return 1.0f / (1.0f + __expf(-x)); }
__device__ __forceinline__ float tanhf_(float x) { return 1.0f - 2.0f / (__expf(2.0f * x) + 1.0f); }
__device__ __forceinline__ float rlane(float v, int k) {
    return __int_as_float(__builtin_amdgcn_readlane(__float_as_int(v), k));
}
// wave-local barrier: LDS ordering only, vmem loads stay in flight
#define BARRIER() asm volatile("s_waitcnt lgkmcnt(0)\n\ts_barrier" ::: "memory")

// 64-k readlane matvec with per-wave register column
__device__ __forceinline__ float rmv(float v, const float (&wc)[64], float a0i) {
    float a0 = a0i, a1 = 0.f, a2 = 0.f, a3 = 0.f;
    #pragma unroll
    for (int k = 0; k < 64; k += 4) {
        a0 += rlane(v, k)     * wc[k];
        a1 += rlane(v, k + 1) * wc[k + 1];
        a2 += rlane(v, k + 2) * wc[k + 2];
        a3 += rlane(v, k + 3) * wc[k + 3];
    }
    return (a0 + a1) + (a2 + a3);
}

// ---------------- precompute kernel (unchanged) ----------------
__global__ __launch_bounds__(256, 2) void ggnn_pre(
    const int* __restrict__ node_slice, const int* __restrict__ type_slice,
    const float* __restrict__ emb_table, const float* __restrict__ type_table,
    const float* __restrict__ W_in,
    const float* __restrict__ Wr, const float* __restrict__ br,
    const float* __restrict__ Wz, const float* __restrict__ bz,
    const float* __restrict__ Wt, const float* __restrict__ bt,
    u16* __restrict__ NTbf, float* __restrict__ Hws)
{
    const int b  = blockIdx.x >> 3;
    const int i0 = (blockIdx.x & 7) * 16;
    const int t = threadIdx.x;
    const int w = t >> 6;
    const int e = t & 63;

    float wc[96];
    float bias = 0.f;
    if (w < 3) {
        const float* W  = (w == 0) ? Wr : (w == 1) ? Wz : Wt;
        const float* bb = (w == 0) ? br : (w == 1) ? bz : bt;
        bias = bb[e];
        #pragma unroll
        for (int k = 0; k < 96; ++k) wc[k] = W[k * 64 + e];
    } else {
        #pragma unroll
        for (int k = 0; k < 64; ++k) wc[k] = W_in[k * 64 + e];
        #pragma unroll
        for (int k = 64; k < 96; ++k) wc[k] = 0.f;
    }

    for (int rr = 0; rr < 16; ++rr) {
        const int row = i0 + rr;
        const int node = node_slice[b * N_ + row];
        const float* ep = emb_table + node * 64;
        if (w < 3) {
            const int typ = type_slice[b * N_ + row];
            const float* tp = type_table + typ * 32;
            float a0 = bias, a1 = 0.f, a2 = 0.f, a3 = 0.f;
            #pragma unroll
            for (int k = 0; k < 32; k += 4) {
                a0 += tp[k]   * wc[k];
                a1 += tp[k+1] * wc[k+1];
                a2 += tp[k+2] * wc[k+2];
                a3 += tp[k+3] * wc[k+3];
            }
            #pragma unroll
            for (int k = 0; k < 64; k += 4) {
                a0 += ep[k]   * wc[32+k];
                a1 += ep[k+1] * wc[32+k+1];
                a2 += ep[k+2] * wc[32+k+2];
                a3 += ep[k+3] * wc[32+k+3];
            }
            NTbf[(b * N_ + row) * 192 + w * 64 + e] = f2b((a0 + a1) + (a2 + a3));
        } else {
            float a0 = 0.f, a1 = 0.f, a2 = 0.f, a3 = 0.f;
            #pragma unroll
            for (int k = 0; k < 64; k += 4) {
                a0 += ep[k]   * wc[k];
                a1 += ep[k+1] * wc[k+1];
                a2 += ep[k+2] * wc[k+2];
                a3 += ep[k+3] * wc[k+3];
            }
            Hws[(b * N_ + row) * 64 + e] = (a0 + a1) + (a2 + a3);
        }
    }
}

// ---------------- main scan kernel ----------------
__global__ __launch_bounds__(256, 1) void ggnn_main(
    const int* __restrict__ rel_matrix,
    const int* __restrict__ input_length, const float* __restrict__ distance,
    const float* __restrict__ rel_table,
    const float* __restrict__ W_in, const float* __restrict__ b_in,
    const float* __restrict__ Wr, const float* __restrict__ Wz, const float* __restrict__ Wt,
    const float* __restrict__ W_co, const float* __restrict__ b_co,
    const float* __restrict__ W1, const float* __restrict__ b1,
    const float* __restrict__ W2, const float* __restrict__ b2,
    const float* __restrict__ W3, const float* __restrict__ b3,
    const float* __restrict__ W4, const float* __restrict__ b4,
    const u16* __restrict__ NTbf, const float* __restrict__ Hws,
    float* __restrict__ out)
{
    __shared__ __align__(16) u32   relW32[51 * 32];       // 6.4 KB, [r][e-pair]
    __shared__ __align__(16) unsigned char relL[128 * 128]; // 16 KB, len-masked
    __shared__ __align__(16) float disc[N_];
    __shared__ __align__(16) float pmax[256];
    __shared__ __align__(16) float r_row[64], z_row[64], v2row[64];
    __shared__ __align__(16) float updH1[64], updH2[64];
    __shared__ __align__(16) float userrow[64], itemrow[64], submrow[64];
    __shared__ __align__(16) float temp[192];
    __shared__ float h1[128];
    __shared__ float h2v[64];
    __shared__ float h3v[32];

    const int b = blockIdx.x;
    const int t = threadIdx.x;
    const int w = t >> 6;
    const int e = t & 63;
    const int len = input_length[b];
    const float NEGINF = -__builtin_inff();

    // ---- staging ----
    if (t < N_) disc[t] = -0.1f * distance[b * N_ + t];

    {   // rel_matrix -> u8, len-masked
        const int4* src = (const int4*)(rel_matrix + b * N_ * N_);
        u32* dst = (u32*)relL;
        for (int c = t; c < 4096; c += 256) {
            int4 v = src[c];
            int j = (c * 4) & 127;
            u32 pk = (u32)((j + 0 < len && v.x) ? v.x : 0)
                   | ((u32)((j + 1 < len && v.y) ? v.y : 0) << 8)
                   | ((u32)((j + 2 < len && v.z) ? v.z : 0) << 16)
                   | ((u32)((j + 3 < len && v.w) ? v.w : 0) << 24);
            dst[c] = pk;
        }
    }
    for (int idx = t; idx < 51 * 32; idx += 256) {        // relW32 = b_in + rel@W_in_bot
        int r = idx >> 5, pp = idx & 31;
        float aA = b_in[2 * pp], aB = b_in[2 * pp + 1];
        #pragma unroll
        for (int k = 0; k < 32; ++k) {
            float rt = rel_table[r * 32 + k];
            aA += rt * W_in[(64 + k) * 64 + 2 * pp];
            aB += rt * W_in[(64 + k) * 64 + 2 * pp + 1];
        }
        relW32[idx] = (u32)f2b(aA) | ((u32)f2b(aB) << 16);
    }

    // per-wave weight column: w0=Wr_bot, w1=Wz_bot, w2=Wt_bot, w3=W_in_top
    float wcol[64];
    {
        const float* wsrc = (w == 0) ? (Wr + 96 * 64) : (w == 1) ? (Wz + 96 * 64)
                          : (w == 2) ? (Wt + 96 * 64) : W_in;
        #pragma unroll
        for (int k = 0; k < 64; ++k) wcol[k] = wsrc[k * 64 + e];
    }

    // H in registers: lane (p,half) of wave w holds e-pair (2p,2p+1) for
    // j = jbase..jbase+15, jbase = 32w + 16*half.
    const int p = e & 31;
    const int half = e >> 5;
    const int jbase = w * 32 + half * 16;
    float hA[16], hB[16];
    {
        const float2* H2 = (const float2*)(Hws + (size_t)b * N_ * 64);
        #pragma unroll
        for (int jj = 0; jj < 16; ++jj) {
            float2 v = H2[(jbase + jj) * 32 + p];
            hA[jj] = v.x; hB[jj] = v.y;
        }
    }

    // NT prefetch (step 0)
    const u16* NTb = NTbf + (size_t)b * N_ * 192;
    u16 ntc = 0;
    if (w < 3) ntc = NTb[w * 64 + e];
    float user_r = 0.f, item_r = 0.f, subm_r = NEGINF;
    __syncthreads();                                      // A0 (full drain)

    float dregp[16];
    #pragma unroll
    for (int jj = 0; jj < 16; ++jj) dregp[jj] = disc[jbase + jj];

    // ---- scan ----
    for (int i = 0; i < len; ++i) {
        // NT prefetch for step i+1 (raw barriers keep it in flight)
        u16 ntp = 0;
        if (w < 3) ntp = NTb[((i + 1) & 127) * 192 + w * 64 + e];

        // rel row for this wave's 32 j (one b128, uniform-per-half addr)
        uint4 rvv = *(const uint4*)(relL + i * N_ + jbase);
        const u32 rvw[4] = {rvv.x, rvv.y, rvv.z, rvv.w};

        // owner wave merges H row i-1 (computed last step as part1+part2)
        if (i > 0) {
            const int prev = i - 1;
            if (w == (prev >> 5)) {
                float2 u1 = ((const float2*)updH1)[p];
                float2 u2 = ((const float2*)updH2)[p];
                float nhA = u1.x + u2.x, nhB = u1.y + u2.y;
                bool hm = (half == ((prev >> 4) & 1));
                const int oj = prev & 15;
                #pragma unroll
                for (int jj = 0; jj < 16; ++jj) {
                    if (jj == oj) {
                        hA[jj] = hm ? nhA : hA[jj];
                        hB[jj] = hm ? nhB : hB[jj];
                    }
                }
            }
        }

        // max phase over this lane's 16 j x 2 e
        float mA = NEGINF, mB = NEGINF;
        #pragma unroll
        for (int jj = 0; jj < 16; ++jj) {
            u32 rr = (rvw[jj >> 2] >> ((jj & 3) * 8)) & 255u;
            u32 pr = relW32[(rr << 5) + p];
            float rwbA = __uint_as_float(pr << 16);
            float rwbB = __uint_as_float(pr & 0xffff0000u);
            float dd = dregp[jj];
            float sA = fmaxf(hA[jj] + rwbA, 0.f) * dd;
            float sB = fmaxf(hB[jj] + rwbB, 0.f) * dd;
            mA = rr ? fmaxf(mA, sA) : mA;
            mB = rr ? fmaxf(mB, sB) : mB;
        }
        // pair-layout -> lane-e: lane e pulls component (e&1) of pair lane
        // (e>>1) from both halves, then maxes.
        {
            int s0 = (e >> 1) << 2, s1 = ((e >> 1) + 32) << 2;
            float v0a = __int_as_float(__builtin_amdgcn_ds_bpermute(s0, __float_as_int(mA)));
            float v0b = __int_as_float(__builtin_amdgcn_ds_bpermute(s0, __float_as_int(mB)));
            float v1a = __int_as_float(__builtin_amdgcn_ds_bpermute(s1, __float_as_int(mA)));
            float v1b = __int_as_float(__builtin_amdgcn_ds_bpermute(s1, __float_as_int(mB)));
            float c0 = (e & 1) ? v0b : v0a;
            float c1 = (e & 1) ? v1b : v1a;
            pmax[(w << 6) + e] = fmaxf(c0, c1);
        }
        BARRIER();                                        // B

        float mm = fmaxf(fmaxf(pmax[e], pmax[64 + e]),
                         fmaxf(pmax[128 + e], pmax[192 + e]));
        float dis0 = (mm == NEGINF) ? 0.f : mm;

        if (w == 0) {                                     // r-gate
            r_row[e] = sigmoidf_(rmv(dis0, wcol, b2f(ntc)));
        } else if (w == 1) {                              // z-gate
            z_row[e] = sigmoidf_(rmv(dis0, wcol, b2f(ntc)));
        }
        BARRIER();                                        // C

        if (w == 2) {                                     // t-gate + update
            float rdp = r_row[e] * dis0;
            float hh = tanhf_(rmv(rdp, wcol, b2f(ntc)));
            float z = z_row[e];
            float zh = z * hh;
            float upd = (1.f - z) * dis0 + zh;
            v2row[e] = zh;
            if (i == 0) user_r = upd;
            subm_r = fmaxf(subm_r, upd);
            item_r = upd;
        } else if (w == 3) {                              // part1 = (1-z)dis0 @ Win
            float v1 = (1.f - z_row[e]) * dis0;
            updH1[e] = rmv(v1, wcol, 0.f);
        }
        BARRIER();                                        // D

        if (w == 3) {                                     // part2 = (z*hh) @ Win
            updH2[e] = rmv(v2row[e], wcol, 0.f);
        }
        ntc = ntp;
        BARRIER();                                        // A (loop top)
    }

    if (w == 2) { userrow[e] = user_r; itemrow[e] = item_r; submrow[e] = subm_r; }
    __syncthreads();

    // ---- epilogue ----
    if (t < 128) {
        const int half2 = t >> 6;               // 0: ua*user, 1: ia*item
        const float* row = (half2 == 0) ? userrow : itemrow;
        float acc = b_co[e];
        #pragma unroll
        for (int k = 0; k < 64; ++k) acc += row[k] * W_co[k * 64 + e];
        #pragma unroll
        for (int k = 0; k < 64; ++k) acc += submrow[k] * W_co[(64 + k) * 64 + e];
        float act = fmaxf(acc, 0.f);
        temp[half2 * 128 + e] = act * row[e];
    } else if (t < 192) {
        temp[64 + (t - 128)] = submrow[t - 128];
    }
    __syncthreads();

    if (t < 128) {
        float acc = b1[t];
        for (int k = 0; k < 192; ++k) acc += temp[k] * W1[k * 128 + t];
        h1[t] = fmaxf(acc, 0.f);
    }
    __syncthreads();
    if (t < 64) {
        float acc = b2[t];
        for (int k = 0; k < 128; ++k) acc += h1[k] * W2[k * 64 + t];
        h2v[t] = fmaxf(acc, 0.f);
    }
    __syncthreads();
    if (t < 32) {
        float acc = b3[t];
        for (int k = 0; k < 64; ++k) acc += h2v[k] * W3[k * 32 + t];
        h3v[t] = fmaxf(acc, 0.f);
    }
    __syncthreads();
    if (t == 0) {
        float acc = b4[0];
        for (int k = 0; k < 32; ++k) acc += h3v[k] * W4[k];
        out[b] = sigmoidf_(acc);
    }
}

extern "C" void kernel_launch(void* const* d_in, const int* in_sizes, int n_in,
                              void* d_out, int out_size, void* d_ws, size_t ws_size,
                              hipStream_t stream)
{
    const int*   node_slice = (const int*)d_in[0];
    const int*   type_slice = (const int*)d_in[1];
    const float* distance   = (const float*)d_in[2];
    const int*   rel_matrix = (const int*)d_in[3];
    const int*   input_len  = (const int*)d_in[4];
    // d_in[5] = isBatch (ignored)
    const float* emb_table  = (const float*)d_in[6];
    const float* type_table = (const float*)d_in[7];
    const float* rel_table  = (const float*)d_in[8];
    const float* W_in = (const float*)d_in[9];  const float* b_in = (const float*)d_in[10];
    const float* Wr   = (const float*)d_in[11]; const float* br   = (const float*)d_in[12];
    const float* Wz   = (const float*)d_in[13]; const float* bz   = (const float*)d_in[14];
    const float* Wt   = (const float*)d_in[15]; const float* bt   = (const float*)d_in[16];
    const float* W_co = (const float*)d_in[17]; const float* b_co = (const float*)d_in[18];
    const float* W1   = (const float*)d_in[19]; const float* b1   = (const float*)d_in[20];
    const float* W2   = (const float*)d_in[21]; const float* b2   = (const float*)d_in[22];
    const float* W3   = (const float*)d_in[23]; const float* b3   = (const float*)d_in[24];
    const float* W4   = (const float*)d_in[25]; const float* b4   = (const float*)d_in[26];

    u16*   NTbf = (u16*)d_ws;                            // 128*128*192 bf16 = 6.29 MB
    float* Hws  = (float*)((char*)d_ws + (size_t)B_ * N_ * 192 * 2); // 4.19 MB

    ggnn_pre<<<dim3(1024), dim3(256), 0, stream>>>(
        node_slice, type_slice, emb_table, type_table,
        W_in, Wr, br, Wz, bz, Wt, bt, NTbf, Hws);

    ggnn_main<<<dim3(B_), dim3(256), 0, stream>>>(
        rel_matrix, input_len, distance, rel_table,
        W_in, b_in, Wr, Wz, Wt, W_co, b_co,
        W1, b1, W2, b2, W3, b3, W4, b4,
        NTbf, Hws, (float*)d_out);
}